// Round 4
// baseline (810.515 us; speedup 1.0000x reference)
//
#include <hip/hip_runtime.h>

#define SEQ   2048
#define BATCH 4096
#define HID   6

typedef float v2 __attribute__((ext_vector_type(2)));

// ---- fast HW math (v_exp_f32 / v_rcp_f32), with asm fallback ----
__device__ __forceinline__ float fexp2(float a) {
#if __has_builtin(__builtin_amdgcn_exp2f)
  return __builtin_amdgcn_exp2f(a);
#else
  float r; asm("v_exp_f32 %0, %1" : "=v"(r) : "v"(a)); return r;
#endif
}
__device__ __forceinline__ float frcp(float a) {
#if __has_builtin(__builtin_amdgcn_rcpf)
  return __builtin_amdgcn_rcpf(a);
#else
  float r; asm("v_rcp_f32 %0, %1" : "=v"(r) : "v"(a)); return r;
#endif
}

// ---- DPP cross-lane move (VALU pipe, no LDS) ----
template <int CTRL>
__device__ __forceinline__ float dppf(float v) {
  int r = __builtin_amdgcn_update_dpp(0, __builtin_bit_cast(int, v), CTRL, 0xF, 0xF, true);
  return __builtin_bit_cast(float, r);
}

// block=128 (2 waves): wave-pairs share x cachelines through the CU's L1 ->
// halves HBM fetch of x. Still 1 wave/SIMD (512 blocks * 2 waves / 256 CUs).
__global__ __launch_bounds__(128, 1) void lstm2_kernel(
    const float* __restrict__ x,
    const float* __restrict__ Wih0, const float* __restrict__ Whh0,
    const float* __restrict__ bih0, const float* __restrict__ bhh0,
    const float* __restrict__ Wih1, const float* __restrict__ Whh1,
    const float* __restrict__ bih1, const float* __restrict__ bhh1,
    const float* __restrict__ W2,   const float* __restrict__ b2,
    float* __restrict__ out)
{
  const int tid = blockIdx.x * 128 + threadIdx.x;
  const int b   = tid >> 4;              // batch element (16 lanes per element)
  const int l   = threadIdx.x & 15;      // lane within group (DPP-row aligned)
  const int u   = l & 7;                 // unit 0..7 (6,7 are pads)
  const int p   = (l >> 3) & 1;          // 0 -> rows {i,f}; 1 -> rows {g,o}
  const int uu  = (u < HID) ? u : (HID - 1);
  const int r0  = p ? (2 * HID + uu) : uu;           // i-row or g-row
  const int r1  = p ? (3 * HID + uu) : (HID + uu);   // f-row or o-row

  // ---- stage all loop-invariant weights as scalars, then PIN them in VGPRs.
  // R3 disasm-model: compiler rematerialized these loads every iteration
  // (~28 VMEM + addr VALU per step). asm "+v" makes the values opaque ->
  // they must stay register-resident.
  float wf[7][8];   // 0:wh0a 1:wh0b 2:wi1a 3:wi1b 4:wh1a 5:wh1b 6:w2r
#pragma unroll
  for (int j = 0; j < 8; ++j) {
    const int k = u ^ j;
    const bool ok = (k < HID);
    wf[0][j] = ok ? Whh0[r0 * HID + k] : 0.f;
    wf[1][j] = ok ? Whh0[r1 * HID + k] : 0.f;
    wf[2][j] = ok ? Wih1[r0 * HID + k] : 0.f;
    wf[3][j] = ok ? Wih1[r1 * HID + k] : 0.f;
    wf[4][j] = ok ? Whh1[r0 * HID + k] : 0.f;
    wf[5][j] = ok ? Whh1[r1 * HID + k] : 0.f;
    wf[6][j] = ok ? W2[k] : 0.f;
  }
  float wxs[4] = {Wih0[r0 * 2 + 0], Wih0[r0 * 2 + 1], Wih0[r1 * 2 + 0], Wih0[r1 * 2 + 1]};
  float bss[4] = {bih0[r0] + bhh0[r0], bih0[r1] + bhh0[r1],
                  bih1[r0] + bhh1[r0], bih1[r1] + bhh1[r1]};
#pragma unroll
  for (int a = 0; a < 7; ++a)
#pragma unroll
    for (int j = 0; j < 8; ++j) asm volatile("" : "+v"(wf[a][j]));
#pragma unroll
  for (int j = 0; j < 4; ++j) {
    asm volatile("" : "+v"(wxs[j]));
    asm volatile("" : "+v"(bss[j]));
  }

  // pack pinned scalars into v2 pairs for v_pk_fma_f32
  v2 wh0a2[4], wh0b2[4], wi1a2[4], wi1b2[4], wh1a2[4], wh1b2[4], w2r2[4];
#pragma unroll
  for (int k = 0; k < 4; ++k) {
    wh0a2[k] = v2{wf[0][2 * k], wf[0][2 * k + 1]};
    wh0b2[k] = v2{wf[1][2 * k], wf[1][2 * k + 1]};
    wi1a2[k] = v2{wf[2][2 * k], wf[2][2 * k + 1]};
    wi1b2[k] = v2{wf[3][2 * k], wf[3][2 * k + 1]};
    wh1a2[k] = v2{wf[4][2 * k], wf[4][2 * k + 1]};
    wh1b2[k] = v2{wf[5][2 * k], wf[5][2 * k + 1]};
    w2r2[k]  = v2{wf[6][2 * k], wf[6][2 * k + 1]};
  }
  const v2 wx0p = v2{wxs[0], wxs[1]};
  const v2 wx1p = v2{wxs[2], wxs[3]};
  const v2 B0A = v2{bss[0], 0.f};
  const v2 B0B = v2{bss[1], 0.f};
  const v2 B1A = v2{bss[2], 0.f};
  const v2 B1B = v2{bss[3], 0.f};
  const float bout = b2[0];

  // act: sigmoid for p=0 rows, tanh for p=1's first row via A*sigmoid(A*a)+Bc
  const float A  = p ? 2.f : 1.f;
  const float Bc = p ? -1.f : 0.f;
  const float K0 = -1.4426950408889634f * A;
  const float KS = -1.4426950408889634f;
  const float KT =  2.8853900817779268f;   // tanh(c) = 1 - 2/(1+exp2(KT*c))

  float c0 = 0.f, c1 = 0.f;
  float h0p = 0.f, h1p = 0.f;
  v2 h0g[4], h1g[4];

  // gate nonlinearity + pair-exchange (xor8 via row_ror:8) + c/h update.
  // rcp(1+exp2(+-inf)) saturates cleanly (0 or 1), NaN-free.
  auto actupd = [&](float a0, float a1, float& c) -> float {
    float g0 = fmaf(A, frcp(1.f + fexp2(a0 * K0)), Bc);   // i (p0) or g (p1)
    float g1 = frcp(1.f + fexp2(a1 * KS));                // f (p0) or o (p1)
    float xg0 = dppf<0x128>(g0);
    float xg1 = dppf<0x128>(g1);
    float m = g0 * xg0;                                   // i*g
    float f = p ? xg1 : g1;
    float o = p ? g1  : xg1;
    c = fmaf(f, c, m);
    float t = fmaf(-2.f, frcp(1.f + fexp2(c * KT)), 1.f);
    return o * t;
  };

  // all-gather h across 8 units into xor-relative v2 pairs g[k] = {h[u^2k], h[u^2k+1]}
  auto gath = [&](float h, v2 (&g)[4]) {
    float t1 = dppf<0xB1>(h);        // xor1 (quad_perm [1,0,3,2])
    float t2 = dppf<0x4E>(h);        // xor2 (quad_perm [2,3,0,1])
    float t3 = dppf<0x4E>(t1);       // xor3
    g[0] = v2{h, t1};
    g[1] = v2{t2, t3};
    g[2] = v2{dppf<0x124>(h),  dppf<0x124>(t1)};   // row_ror:4 == xor4/xor5 (half-replicated)
    g[3] = v2{dppf<0x124>(t2), dppf<0x124>(t3)};   // xor6/xor7
  };

  auto dot8 = [](const v2 (&w)[4], const v2 (&g)[4], v2 acc) -> v2 {
#pragma unroll
    for (int k = 0; k < 4; ++k) acc = __builtin_elementwise_fma(w[k], g[k], acc);
    return acc;
  };

  const v2* x2 = (const v2*)x;
  // x prefetch queue, depth 4; invariant at loop-entry t: (xc,xn1,xn2,xn3)=(x[t..t+3])
  v2 xc  = x2[(size_t)0 * BATCH + b];
  v2 xn1 = x2[(size_t)1 * BATCH + b];
  v2 xn2 = x2[(size_t)2 * BATCH + b];
  v2 xn3 = x2[(size_t)3 * BATCH + b];

  // t = 0 peel: L0 only (h0[-1] = 0); refill queue
  {
    v2 A0 = __builtin_elementwise_fma(wx0p, xc, B0A);
    v2 A1 = __builtin_elementwise_fma(wx1p, xc, B0B);
    h0p = actupd(A0.x + A0.y, A1.x + A1.y, c0);
    v2 xf = x2[(size_t)4 * BATCH + b];
    xc = xn1; xn1 = xn2; xn2 = xn3; xn3 = xf;
  }

  // t = 1 peel: L0[1] || L1[0], no out row yet
  {
    v2 xf = x2[(size_t)5 * BATCH + b];
    gath(h0p, h0g);   // h0[0]
    gath(h1p, h1g);   // h1[-1] = 0
    v2 A00 = dot8(wh0a2, h0g, __builtin_elementwise_fma(wx0p, xc, B0A));
    v2 A01 = dot8(wh0b2, h0g, __builtin_elementwise_fma(wx1p, xc, B0B));
    v2 A10 = dot8(wh1a2, h1g, dot8(wi1a2, h0g, B1A));
    v2 A11 = dot8(wh1b2, h1g, dot8(wi1b2, h0g, B1B));
    h0p = actupd(A00.x + A00.y, A01.x + A01.y, c0);   // h0[1]
    h1p = actupd(A10.x + A10.y, A11.x + A11.y, c1);   // h1[0]
    xc = xn1; xn1 = xn2; xn2 = xn3; xn3 = xf;
  }

  // iteration t: L0[t] (x[t], h0[t-1]) || L1[t-1] (h0[t-1], h1[t-2]) independent chains.
  // unroll 4: queue shifts become register renaming, no per-step v_movs.
#pragma unroll 4
  for (int t = 2; t < SEQ; ++t) {
    int tf = t + 4; tf = (tf < SEQ) ? tf : (SEQ - 1);
    v2 xf = x2[(size_t)tf * BATCH + b];

    gath(h0p, h0g);   // h0[t-1]
    gath(h1p, h1g);   // h1[t-2]

    v2 A00 = dot8(wh0a2, h0g, __builtin_elementwise_fma(wx0p, xc, B0A));
    v2 A01 = dot8(wh0b2, h0g, __builtin_elementwise_fma(wx1p, xc, B0B));
    v2 A10 = dot8(wh1a2, h1g, dot8(wi1a2, h0g, B1A));
    v2 A11 = dot8(wh1b2, h1g, dot8(wi1b2, h0g, B1B));

    // out row t-2 from the already-gathered h1[t-2]
    v2 AO = dot8(w2r2, h1g, v2{bout, 0.f});
    if (l == 0) out[(size_t)(t - 2) * BATCH + b] = AO.x + AO.y;

    float h0c = actupd(A00.x + A00.y, A01.x + A01.y, c0);   // h0[t]
    float h1c = actupd(A10.x + A10.y, A11.x + A11.y, c1);   // h1[t-1]

    h0p = h0c; h1p = h1c;
    xc = xn1; xn1 = xn2; xn2 = xn3; xn3 = xf;
  }

  // epilogue: rows S-2 and S-1
  {
    gath(h0p, h0g);   // h0[S-1]
    gath(h1p, h1g);   // h1[S-2]
    {
      v2 AO = dot8(w2r2, h1g, v2{bout, 0.f});
      if (l == 0) out[(size_t)(SEQ - 2) * BATCH + b] = AO.x + AO.y;
    }
    v2 A10 = dot8(wh1a2, h1g, dot8(wi1a2, h0g, B1A));
    v2 A11 = dot8(wh1b2, h1g, dot8(wi1b2, h0g, B1B));
    float h1c = actupd(A10.x + A10.y, A11.x + A11.y, c1);   // h1[S-1]
    gath(h1c, h1g);
    v2 AO = dot8(w2r2, h1g, v2{bout, 0.f});
    if (l == 0) out[(size_t)(SEQ - 1) * BATCH + b] = AO.x + AO.y;
  }
}

extern "C" void kernel_launch(void* const* d_in, const int* in_sizes, int n_in,
                              void* d_out, int out_size, void* d_ws, size_t ws_size,
                              hipStream_t stream) {
  const float* x    = (const float*)d_in[0];
  const float* Wih0 = (const float*)d_in[1];
  const float* Whh0 = (const float*)d_in[2];
  const float* bih0 = (const float*)d_in[3];
  const float* bhh0 = (const float*)d_in[4];
  const float* Wih1 = (const float*)d_in[5];
  const float* Whh1 = (const float*)d_in[6];
  const float* bih1 = (const float*)d_in[7];
  const float* bhh1 = (const float*)d_in[8];
  const float* W2   = (const float*)d_in[9];
  const float* b2   = (const float*)d_in[10];
  float* out = (float*)d_out;

  dim3 grid(BATCH * 16 / 128);   // 512 blocks x 2 waves = 1 wave/SIMD chip-wide
  dim3 block(128);
  hipLaunchKernelGGL(lstm2_kernel, grid, block, 0, stream,
                     x, Wih0, Whh0, bih0, bhh0, Wih1, Whh1, bih1, bhh1, W2, b2, out);
}

// Round 5
// 697.713 us; speedup vs baseline: 1.1617x; 1.1617x over previous
//
#include <hip/hip_runtime.h>

#define SEQ   2048
#define BATCH 4096
#define HID   6
#define BLK   256   // 16 elements per block; 256 blocks -> 1 block/CU, 1 wave/SIMD

typedef float v2 __attribute__((ext_vector_type(2)));

// ---- fast HW math (v_exp_f32 / v_rcp_f32), with asm fallback ----
__device__ __forceinline__ float fexp2(float a) {
#if __has_builtin(__builtin_amdgcn_exp2f)
  return __builtin_amdgcn_exp2f(a);
#else
  float r; asm("v_exp_f32 %0, %1" : "=v"(r) : "v"(a)); return r;
#endif
}
__device__ __forceinline__ float frcp(float a) {
#if __has_builtin(__builtin_amdgcn_rcpf)
  return __builtin_amdgcn_rcpf(a);
#else
  float r; asm("v_rcp_f32 %0, %1" : "=v"(r) : "v"(a)); return r;
#endif
}

// ---- DPP cross-lane move (VALU pipe, no LDS) ----
template <int CTRL>
__device__ __forceinline__ float dppf(float v) {
  int r = __builtin_amdgcn_update_dpp(0, __builtin_bit_cast(int, v), CTRL, 0xF, 0xF, true);
  return __builtin_bit_cast(float, r);
}

__global__ __launch_bounds__(BLK, 1) void lstm2_kernel(
    const float* __restrict__ x,
    const float* __restrict__ Wih0, const float* __restrict__ Whh0,
    const float* __restrict__ bih0, const float* __restrict__ bhh0,
    const float* __restrict__ Wih1, const float* __restrict__ Whh1,
    const float* __restrict__ bih1, const float* __restrict__ bhh1,
    const float* __restrict__ W2,   const float* __restrict__ b2,
    float* __restrict__ out)
{
  // output row buffer: 64 steps x 16 elements; flushed as full 64B lines.
  // Purpose: keep global_store OUT of the recurrence's vmcnt queue (R4 theory:
  // per-step stores serialized the loop on HBM write latency).
  __shared__ float obuf[64][16];

  const int tidb = threadIdx.x;
  const int g    = tidb >> 4;            // element group 0..15 within block
  const int b    = blockIdx.x * 16 + g;  // batch element
  const int l    = tidb & 15;            // lane within group (DPP-row aligned)
  const int u    = l & 7;                // unit 0..7 (6,7 pads)
  const int p    = (l >> 3) & 1;         // 0 -> rows {i,f}; 1 -> rows {g,o}
  const int uu   = (u < HID) ? u : (HID - 1);
  const int r0   = p ? (2 * HID + uu) : uu;           // i-row or g-row
  const int r1   = p ? (3 * HID + uu) : (HID + uu);   // f-row or o-row

  // Weights packed as v2 over j-pairs: slot k holds {W[u^(2k)], W[u^(2k+1)]}.
  v2 wh0a2[4], wh0b2[4], wi1a2[4], wi1b2[4], wh1a2[4], wh1b2[4], w2r2[4];
#pragma unroll
  for (int k = 0; k < 4; ++k) {
    const int k0 = u ^ (2 * k), k1 = u ^ (2 * k + 1);
    const bool ok0 = (k0 < HID), ok1 = (k1 < HID);
    wh0a2[k] = v2{ok0 ? Whh0[r0 * HID + k0] : 0.f, ok1 ? Whh0[r0 * HID + k1] : 0.f};
    wh0b2[k] = v2{ok0 ? Whh0[r1 * HID + k0] : 0.f, ok1 ? Whh0[r1 * HID + k1] : 0.f};
    wi1a2[k] = v2{ok0 ? Wih1[r0 * HID + k0] : 0.f, ok1 ? Wih1[r0 * HID + k1] : 0.f};
    wi1b2[k] = v2{ok0 ? Wih1[r1 * HID + k0] : 0.f, ok1 ? Wih1[r1 * HID + k1] : 0.f};
    wh1a2[k] = v2{ok0 ? Whh1[r0 * HID + k0] : 0.f, ok1 ? Whh1[r0 * HID + k1] : 0.f};
    wh1b2[k] = v2{ok0 ? Whh1[r1 * HID + k0] : 0.f, ok1 ? Whh1[r1 * HID + k1] : 0.f};
    w2r2[k]  = v2{ok0 ? W2[k0] : 0.f,             ok1 ? W2[k1] : 0.f};
  }
  const v2 wx0p = v2{Wih0[r0 * 2 + 0], Wih0[r0 * 2 + 1]};
  const v2 wx1p = v2{Wih0[r1 * 2 + 0], Wih0[r1 * 2 + 1]};
  const v2 B0A = v2{bih0[r0] + bhh0[r0], 0.f};
  const v2 B0B = v2{bih0[r1] + bhh0[r1], 0.f};
  const v2 B1A = v2{bih1[r0] + bhh1[r0], 0.f};
  const v2 B1B = v2{bih1[r1] + bhh1[r1], 0.f};
  const float bout = b2[0];

  // act: sigmoid for p=0 rows, tanh for p=1's first row via A*sigmoid(A*a)+Bc
  const float A  = p ? 2.f : 1.f;
  const float Bc = p ? -1.f : 0.f;
  const float K0 = -1.4426950408889634f * A;
  const float KS = -1.4426950408889634f;
  const float KT =  2.8853900817779268f;   // tanh(c) = 1 - 2/(1+exp2(KT*c))

  float c0 = 0.f, c1 = 0.f;
  float h0p = 0.f, h1p = 0.f;
  v2 h0g[4], h1g[4];

  // gate nonlinearity + pair-exchange (xor8 via row_ror:8) + c/h update.
  // rcp(1+exp2(+-inf)) saturates cleanly (0 or 1), NaN-free.
  auto actupd = [&](float a0, float a1, float& c) -> float {
    float g0 = fmaf(A, frcp(1.f + fexp2(a0 * K0)), Bc);   // i (p0) or g (p1)
    float g1 = frcp(1.f + fexp2(a1 * KS));                // f (p0) or o (p1)
    float xg0 = dppf<0x128>(g0);
    float xg1 = dppf<0x128>(g1);
    float m = g0 * xg0;                                   // i*g
    float f = p ? xg1 : g1;
    float o = p ? g1  : xg1;
    c = fmaf(f, c, m);
    float t = fmaf(-2.f, frcp(1.f + fexp2(c * KT)), 1.f);
    return o * t;
  };

  // all-gather h across 8 units into xor-relative v2 pairs g[k] = {h[u^2k], h[u^2k+1]}
  auto gath = [&](float h, v2 (&g)[4]) {
    float t1 = dppf<0xB1>(h);        // xor1 (quad_perm [1,0,3,2])
    float t2 = dppf<0x4E>(h);        // xor2 (quad_perm [2,3,0,1])
    float t3 = dppf<0x4E>(t1);       // xor3
    g[0] = v2{h, t1};
    g[1] = v2{t2, t3};
    g[2] = v2{dppf<0x124>(h),  dppf<0x124>(t1)};   // row_ror:4 == xor4/xor5 (half-replicated)
    g[3] = v2{dppf<0x124>(t2), dppf<0x124>(t3)};   // xor6/xor7
  };

  auto dot8 = [](const v2 (&w)[4], const v2 (&g)[4], v2 acc) -> v2 {
#pragma unroll
    for (int k = 0; k < 4; ++k) acc = __builtin_elementwise_fma(w[k], g[k], acc);
    return acc;
  };

  // bulk flush: 64 rows x 16 elements as one float4 store per lane (full 64B lines)
  auto flush = [&](int rbase) {
    const int row = tidb >> 2, j = tidb & 3;
    float4 vv = *(const float4*)&obuf[row][j * 4];
    *(float4*)&out[(size_t)(rbase + row) * BATCH + blockIdx.x * 16 + j * 4] = vv;
  };

  const v2* x2 = (const v2*)x;
  // x prefetch queue, depth 4; invariant at loop-entry t: (xc,xn1,xn2,xn3)=(x[t..t+3])
  v2 xc  = x2[(size_t)0 * BATCH + b];
  v2 xn1 = x2[(size_t)1 * BATCH + b];
  v2 xn2 = x2[(size_t)2 * BATCH + b];
  v2 xn3 = x2[(size_t)3 * BATCH + b];

  // t = 0 peel: L0 only (h0[-1] = 0); refill queue
  {
    v2 A0 = __builtin_elementwise_fma(wx0p, xc, B0A);
    v2 A1 = __builtin_elementwise_fma(wx1p, xc, B0B);
    h0p = actupd(A0.x + A0.y, A1.x + A1.y, c0);
    v2 xf = x2[(size_t)4 * BATCH + b];
    xc = xn1; xn1 = xn2; xn2 = xn3; xn3 = xf;
  }

  // iteration t: L0[t] (x[t], h0[t-1]) || L1[t-1] (h0[t-1], h1[t-2]) independent chains
#pragma unroll 1
  for (int t = 1; t < SEQ; ++t) {
    int tf = t + 4; tf = (tf < SEQ) ? tf : (SEQ - 1);
    v2 xf = x2[(size_t)tf * BATCH + b];

    gath(h0p, h0g);   // h0[t-1]
    gath(h1p, h1g);   // h1[t-2]

    v2 A00 = dot8(wh0a2, h0g, __builtin_elementwise_fma(wx0p, xc, B0A));
    v2 A01 = dot8(wh0b2, h0g, __builtin_elementwise_fma(wx1p, xc, B0B));
    v2 A10 = dot8(wh1a2, h1g, dot8(wi1a2, h0g, B1A));
    v2 A11 = dot8(wh1b2, h1g, dot8(wi1b2, h0g, B1B));

    // out row t-2 from the already-gathered h1[t-2] -> LDS buffer (no global store here)
    if (t >= 2) {
      const int r = t - 2;
      v2 AO = dot8(w2r2, h1g, v2{bout, 0.f});
      if (l == 0) obuf[r & 63][g] = AO.x + AO.y;
      if ((r & 63) == 63) {          // uniform branch
        __syncthreads();
        flush(r - 63);
        __syncthreads();
      }
    }

    float h0c = actupd(A00.x + A00.y, A01.x + A01.y, c0);   // h0[t]
    float h1c = actupd(A10.x + A10.y, A11.x + A11.y, c1);   // h1[t-1]

    h0p = h0c; h1p = h1c;
    xc = xn1; xn1 = xn2; xn2 = xn3; xn3 = xf;
  }

  // epilogue: rows S-2 and S-1 -> slots 62, 63, then final flush
  {
    gath(h0p, h0g);   // h0[S-1]
    gath(h1p, h1g);   // h1[S-2]
    {
      v2 AO = dot8(w2r2, h1g, v2{bout, 0.f});
      if (l == 0) obuf[62][g] = AO.x + AO.y;
    }
    v2 A10 = dot8(wh1a2, h1g, dot8(wi1a2, h0g, B1A));
    v2 A11 = dot8(wh1b2, h1g, dot8(wi1b2, h0g, B1B));
    float h1c = actupd(A10.x + A10.y, A11.x + A11.y, c1);   // h1[S-1]
    gath(h1c, h1g);
    v2 AO = dot8(w2r2, h1g, v2{bout, 0.f});
    if (l == 0) obuf[63][g] = AO.x + AO.y;
    __syncthreads();
    flush(SEQ - 64);
  }
}

extern "C" void kernel_launch(void* const* d_in, const int* in_sizes, int n_in,
                              void* d_out, int out_size, void* d_ws, size_t ws_size,
                              hipStream_t stream) {
  const float* x    = (const float*)d_in[0];
  const float* Wih0 = (const float*)d_in[1];
  const float* Whh0 = (const float*)d_in[2];
  const float* bih0 = (const float*)d_in[3];
  const float* bhh0 = (const float*)d_in[4];
  const float* Wih1 = (const float*)d_in[5];
  const float* Whh1 = (const float*)d_in[6];
  const float* bih1 = (const float*)d_in[7];
  const float* bhh1 = (const float*)d_in[8];
  const float* W2   = (const float*)d_in[9];
  const float* b2   = (const float*)d_in[10];
  float* out = (float*)d_out;

  dim3 grid(BATCH * 16 / BLK);   // 256 blocks -> 1 block/CU, 4 waves = 1 wave/SIMD
  dim3 block(BLK);
  hipLaunchKernelGGL(lstm2_kernel, grid, block, 0, stream,
                     x, Wih0, Whh0, bih0, bhh0, Wih1, Whh1, bih1, bhh1, W2, b2, out);
}